// Round 10
// baseline (100.339 us; speedup 1.0000x reference)
//
#include <hip/hip_runtime.h>
#include <math.h>

#define B_SZ 2048
#define R_SZ 64
#define QT 8                          // q rows per kde block
#define NSPLIT 2                      // s-range halves
#define KDE_BLOCKS (B_SZ / QT * NSPLIT)   // 512 blocks * 16 waves = 32 waves/CU

#define B_POW_NEG02 0.217637640824031f   // 2048^-0.2 = 2^-2.2
#define SQRT_2PI 2.5066282746310002f
#define LOG2E 1.44269504088896340736f

// native v_exp_f32 (exp2)
extern "C" __device__ float __ocml_native_exp2_f32(float);

typedef __attribute__((ext_vector_type(2))) float f32x2;  // -> v_pk_* f32 ops

// ---------------------------------------------------------------------------
// ws layout (floats):
//   [0:64)    lscale        = 1/(B*h*sqrt(2pi))
//   [64:128)  cov_partial
//   [160]     ent_acc       (own line)
//   [192]     done2         (int, own line)
//   [256:256+131072)        U = kscale[r]*A  (prescaled, 512 KB)
//   [131328:...)            density (2 atomic adds per element, 512 KB)
// ---------------------------------------------------------------------------

// Kernel 1: stats + Gram row + cov row + U prescale + density/flag zeroing.
__global__ __launch_bounds__(1024) void cov_stats_kernel(const float* __restrict__ A,
                                                         float* __restrict__ U,
                                                         float* __restrict__ density,
                                                         float* __restrict__ lscale,
                                                         float* __restrict__ cov_partial,
                                                         float* __restrict__ ent_acc,
                                                         int* __restrict__ done2) {
    int i = blockIdx.x;
    int tid = threadIdx.x;
    int j = tid & 63, bg = tid >> 6;          // 16 b-groups

    float g = 0.f, sj = 0.f, s2j = 0.f;
#pragma unroll 4
    for (int b = bg; b < B_SZ; b += 16) {
        float ai = A[b * R_SZ + i];           // wave-uniform broadcast
        float aj = A[b * R_SZ + j];           // coalesced
        g = fmaf(ai, aj, g);
        sj += aj;
        s2j = fmaf(aj, aj, s2j);
    }

    __shared__ float gred[16][64], sred[16][64], s2red[16][64];
    __shared__ float gfin[64], sfin[64], hs[64];
    gred[bg][j] = g; sred[bg][j] = sj; s2red[bg][j] = s2j;
    __syncthreads();
    if (tid < 64) {
        float G = 0.f, S = 0.f, S2 = 0.f;
#pragma unroll
        for (int t = 0; t < 16; ++t) { G += gred[t][j]; S += sred[t][j]; S2 += s2red[t][j]; }
        gfin[j] = G;
        sfin[j] = S;
        float m = S * (1.f / (float)B_SZ);
        float var = (S2 - S * m) * (1.f / (float)(B_SZ - 1));   // ddof=1
        var = fmaxf(var, 0.f);
        float h = fmaxf(1.06f * sqrtf(var) * B_POW_NEG02, 1e-4f);
        hs[j] = sqrtf(0.5f * LOG2E) / h;      // exp2(-(k*d)^2) = exp(-0.5(d/h)^2)
        if (i == 0) lscale[j] = 1.0f / ((float)B_SZ * h * SQRT_2PI);
    }
    __syncthreads();
    if (tid < 64) {                            // covariance row i
        float m_j = sfin[j] * (1.f / (float)B_SZ);
        float m_i = sfin[i] * (1.f / (float)B_SZ);
        float cov = (gfin[j] - (float)B_SZ * m_i * m_j) * (1.f / (float)(B_SZ - 1));
        float v = (j == i) ? 0.f : cov * cov;
        for (int off = 32; off > 0; off >>= 1) v += __shfl_down(v, off, 64);
        if (j == 0) cov_partial[i] = v;
    }
    if (i == 0 && tid == 64) { *ent_acc = 0.f; *done2 = 0; }

    // prescale U rows + zero density (64 blocks x 2048 elems each, exact)
    int base = i * (32 * R_SZ);
    float k0 = hs[tid & 63];
    U[base + tid]        = A[base + tid]        * k0;
    U[base + 1024 + tid] = A[base + 1024 + tid] * k0;
    density[base + tid] = 0.f;
    density[base + 1024 + tid] = 0.f;
}

// ---------------------------------------------------------------------------
// Kernel 2: pairwise KDE, QT=8, s-range split in halves for full occupancy.
// 512 blocks x 1024 thr -> 8192 waves = 32 waves/CU (8/SIMD). Block
// (g = bid>>1, half = bid&1): q rows [8g, 8g+8), s in [1024*half, +1024).
// Wave sg handles s = s0 + sg + 16k, k<64, 8-deep register prefetch.
// Row partials LDS-reduced, then ONE global native-fadd per (row,r)
// per block (2 writers/address total). No atomics in the loop.
// ---------------------------------------------------------------------------
__global__ __launch_bounds__(1024) void kde_kernel(const float* __restrict__ U,
                                                   float* __restrict__ density) {
    int tid = threadIdx.x;
    int r = tid & 63, sg = tid >> 6;
    int g = blockIdx.x >> 1;
    int half = blockIdx.x & 1;
    int q0 = g * QT;

    f32x2 uq01 = { U[(q0 + 0) * R_SZ + r], U[(q0 + 1) * R_SZ + r] };
    f32x2 uq23 = { U[(q0 + 2) * R_SZ + r], U[(q0 + 3) * R_SZ + r] };
    f32x2 uq45 = { U[(q0 + 4) * R_SZ + r], U[(q0 + 5) * R_SZ + r] };
    f32x2 uq67 = { U[(q0 + 6) * R_SZ + r], U[(q0 + 7) * R_SZ + r] };
    f32x2 c01 = { 0.f, 0.f }, c23 = { 0.f, 0.f };
    f32x2 c45 = { 0.f, 0.f }, c67 = { 0.f, 0.f };

#define KDE_BODY(usv)                                                          \
    {                                                                          \
        f32x2 uss = { (usv), (usv) };                                          \
        f32x2 d01 = uq01 - uss, d23 = uq23 - uss;                              \
        f32x2 d45 = uq45 - uss, d67 = uq67 - uss;                              \
        f32x2 n01 = -d01 * d01, n23 = -d23 * d23;                              \
        f32x2 n45 = -d45 * d45, n67 = -d67 * d67;                              \
        f32x2 e01 = { __ocml_native_exp2_f32(n01.x), __ocml_native_exp2_f32(n01.y) }; \
        f32x2 e23 = { __ocml_native_exp2_f32(n23.x), __ocml_native_exp2_f32(n23.y) }; \
        f32x2 e45 = { __ocml_native_exp2_f32(n45.x), __ocml_native_exp2_f32(n45.y) }; \
        f32x2 e67 = { __ocml_native_exp2_f32(n67.x), __ocml_native_exp2_f32(n67.y) }; \
        c01 += e01; c23 += e23; c45 += e45; c67 += e67;                        \
    }

    // wave sg consumes s = half*1024 + sg + 16k, k = 0..63 (stride 1024 elems)
    const float* Up = U + (half * 1024 + sg) * R_SZ + r;
    float p[8];
#pragma unroll
    for (int j = 0; j < 8; ++j) p[j] = Up[j * 1024];   // prologue: 8 in flight

    int li = 8 * 1024;
#pragma unroll 1
    for (int k = 0; k < 7; ++k) {                      // 7 x 8 = 56 consumed
#pragma unroll
        for (int j = 0; j < 8; ++j) {
            float us = p[j];
            p[j] = Up[li + j * 1024];                  // prefetch group k+1
            KDE_BODY(us);
        }
        li += 8 * 1024;
    }
#pragma unroll
    for (int j = 0; j < 8; ++j) KDE_BODY(p[j]);        // drain last 8

#undef KDE_BODY

    // cross-wave reduction of the 8 query-row partials (32 KB LDS)
    __shared__ float red[16][QT][64];
    red[sg][0][r] = c01.x; red[sg][1][r] = c01.y;
    red[sg][2][r] = c23.x; red[sg][3][r] = c23.y;
    red[sg][4][r] = c45.x; red[sg][5][r] = c45.y;
    red[sg][6][r] = c67.x; red[sg][7][r] = c67.y;
    __syncthreads();
    if (sg < QT) {                             // wave sg owns query row q0+sg
        float S = 0.f;
#pragma unroll
        for (int t = 0; t < 16; ++t) S += red[t][sg][r];
        unsafeAtomicAdd(&density[(q0 + sg) * R_SZ + r], S);  // native fadd, 2 writers
    }
}

// ---------------------------------------------------------------------------
// Kernel 3: entropy over assembled density + grid-final fold.
// 64 blocks x 1024; 2 elems/thread; last block folds cov+ent -> out[0].
// ---------------------------------------------------------------------------
__global__ __launch_bounds__(1024) void entropy_kernel(const float* __restrict__ density,
                                                       const float* __restrict__ lscale,
                                                       const float* __restrict__ cov_partial,
                                                       float* __restrict__ ent_acc,
                                                       int* __restrict__ done2,
                                                       float* __restrict__ out) {
    int tid = threadIdx.x;
    int r = tid & 63, sg = tid >> 6;
    float ls = lscale[r];
    int f = blockIdx.x * 2048 + tid;
    float v = __logf(fmaf(density[f], ls, 1e-8f))
            + __logf(fmaf(density[f + 1024], ls, 1e-8f));
    for (int off = 32; off > 0; off >>= 1) v += __shfl_down(v, off, 64);
    __shared__ float wr[16];
    if (r == 0) wr[sg] = v;
    __syncthreads();
    __shared__ int lastflag;
    if (tid == 0) {
        float s = 0.f;
#pragma unroll
        for (int w = 0; w < 16; ++w) s += wr[w];
        atomicAdd(ent_acc, s);             // once per block
        __threadfence();
        int prev = atomicAdd(done2, 1);
        lastflag = (prev == 63);
    }
    __syncthreads();
    if (lastflag && tid < 64) {            // grid-final fold in last block
        __threadfence();
        float v2 = cov_partial[tid];
        for (int off = 32; off > 0; off >>= 1) v2 += __shfl_down(v2, off, 64);
        if (tid == 0) {
            float ent = __hip_atomic_load(ent_acc, __ATOMIC_ACQUIRE,
                                          __HIP_MEMORY_SCOPE_AGENT);
            out[0] = ent * (1.0f / ((float)B_SZ * (float)R_SZ)) + v2;
        }
    }
}

extern "C" void kernel_launch(void* const* d_in, const int* in_sizes, int n_in,
                              void* d_out, int out_size, void* d_ws, size_t ws_size,
                              hipStream_t stream) {
    const float* A = (const float*)d_in[0];
    float* out = (float*)d_out;

    float* wsf = (float*)d_ws;
    float* lscale      = wsf;                 // 64
    float* cov_partial = wsf + 64;            // 64
    float* ent_acc     = wsf + 160;           // isolated line
    int*   done2       = (int*)(wsf + 192);
    float* U           = wsf + 256;           // 2048*64
    float* density     = wsf + 256 + B_SZ * R_SZ;

    cov_stats_kernel<<<R_SZ, 1024, 0, stream>>>(A, U, density, lscale, cov_partial,
                                                ent_acc, done2);
    kde_kernel<<<KDE_BLOCKS, 1024, 0, stream>>>(U, density);
    entropy_kernel<<<64, 1024, 0, stream>>>(density, lscale, cov_partial,
                                            ent_acc, done2, out);
}